// Round 6
// baseline (208.354 us; speedup 1.0000x reference)
//
#include <hip/hip_runtime.h>
#include <math.h>

#define N_NODES 50000
#define HID 128
#define N_EDGES 600000

typedef __attribute__((ext_vector_type(8))) short s16x8;
typedef __attribute__((ext_vector_type(4))) float f32x4;

// RNE float -> bf16 bits (finite inputs only)
__device__ __forceinline__ ushort f2b(float f) {
    uint x = __builtin_bit_cast(uint, f);
    uint r = (x + 0x7FFFu + ((x >> 16) & 1u)) >> 16;
    return (ushort)r;
}
__device__ __forceinline__ float b2f(ushort u) {
    return __builtin_bit_cast(float, (uint)u << 16);
}

// ---------------------------------------------------------------- degree ----
__global__ void zero_cnt_kernel(int* cnt, int n) {
    int i = blockIdx.x * blockDim.x + threadIdx.x;
    if (i < n) cnt[i] = 0;
}

__global__ void count_deg_kernel(const int* __restrict__ dst, int* cnt, int e) {
    int i = blockIdx.x * blockDim.x + threadIdx.x;
    if (i < e) atomicAdd(&cnt[dst[i]], 1);
}

// fused: dinv[i] = rsqrt(cnt[i]+1)  AND  bsum[blk] = sum(cnt) for the scan
__global__ __launch_bounds__(256) void reduce_dinv_kernel(
        const int* __restrict__ cnt, float* __restrict__ dinv,
        int* __restrict__ bsum, int n) {
    int i = blockIdx.x * 256 + threadIdx.x;
    int v = (i < n) ? cnt[i] : 0;
    if (i < n) dinv[i] = rsqrtf((float)(v + 1));   // +1 self-loop
#pragma unroll
    for (int off = 32; off >= 1; off >>= 1) v += __shfl_xor(v, off);
    __shared__ int ws[4];
    if ((threadIdx.x & 63) == 0) ws[threadIdx.x >> 6] = v;
    __syncthreads();
    if (threadIdx.x == 0) bsum[blockIdx.x] = ws[0] + ws[1] + ws[2] + ws[3];
}

__global__ __launch_bounds__(256) void scan_bsum_kernel(int* bsum, int nb) {
    int t = threadIdx.x;
    int v = (t < nb) ? bsum[t] : 0;
    int x = v;
#pragma unroll
    for (int off = 1; off < 64; off <<= 1) {
        int y = __shfl_up(x, off);
        if ((t & 63) >= off) x += y;
    }
    __shared__ int wtot[4];
    if ((t & 63) == 63) wtot[t >> 6] = x;
    __syncthreads();
    int add = 0;
    for (int w = 0; w < (t >> 6); ++w) add += wtot[w];
    if (t < nb) bsum[t] = x - v + add;   // exclusive
}

__global__ __launch_bounds__(256) void scan_block_kernel(
        const int* __restrict__ cnt, const int* __restrict__ bOff,
        int* __restrict__ offs, int n) {
    int i = blockIdx.x * 256 + threadIdx.x;
    int v = (i < n) ? cnt[i] : 0;
    int x = v;
#pragma unroll
    for (int off = 1; off < 64; off <<= 1) {
        int y = __shfl_up(x, off);
        if ((threadIdx.x & 63) >= off) x += y;
    }
    __shared__ int wtot[4];
    if ((threadIdx.x & 63) == 63) wtot[threadIdx.x >> 6] = x;
    __syncthreads();
    int add = bOff[blockIdx.x];
    for (int w = 0; w < (threadIdx.x >> 6); ++w) add += wtot[w];
    if (i < n) offs[i] = x - v + add;    // exclusive scan = segment start
}

__global__ void fill_csr_kernel(const int* __restrict__ src,
                                const int* __restrict__ dst,
                                int* __restrict__ offs,
                                int* __restrict__ srcPerm, int e) {
    int i = blockIdx.x * blockDim.x + threadIdx.x;
    if (i < e) {
        int pos = atomicAdd(&offs[dst[i]], 1);
        srcPerm[pos] = src[i];
    }
}

// ------------------------------------------------------------ MFMA GEMM -----
// H(bf16)[r][c] = dinv[r] * (A[r][:] @ W[:][c]),  M x 128 @ 128 x 128.
template<bool AFP32>
__global__ __launch_bounds__(256) void gemm_mfma_kernel(
        const void* __restrict__ Ap, const float* __restrict__ W,
        const float* __restrict__ dinv, ushort* __restrict__ H, int M) {
    __shared__ ushort Wt[HID * 136];
    uint* Wt32 = (uint*)Wt;
    for (int idx = threadIdx.x; idx < HID * 64; idx += 256) {
        int k2 = idx >> 7;            // k pair 0..63
        int n  = idx & 127;
        float w0 = W[(2 * k2) * HID + n];
        float w1 = W[(2 * k2 + 1) * HID + n];
        Wt32[n * 68 + k2] = (uint)f2b(w0) | ((uint)f2b(w1) << 16);
    }
    __syncthreads();

    const int l  = threadIdx.x & 63;
    const int wv = threadIdx.x >> 6;
    const int r0 = blockIdx.x * 64 + wv * 16;
    if (r0 >= M) return;              // M % 16 == 0 -> whole waves only
    const int arow = r0 + (l & 15);
    const int kg = l >> 4;            // 0..3

    s16x8 afr[4];
    if (AFP32) {
        const float* A = (const float*)Ap + (long)arow * HID;
#pragma unroll
        for (int ks = 0; ks < 4; ++ks) {
            int k0 = ks * 32 + kg * 8;
            float4 a0 = *(const float4*)(A + k0);
            float4 a1 = *(const float4*)(A + k0 + 4);
            s16x8 v;
            v[0] = (short)f2b(a0.x); v[1] = (short)f2b(a0.y);
            v[2] = (short)f2b(a0.z); v[3] = (short)f2b(a0.w);
            v[4] = (short)f2b(a1.x); v[5] = (short)f2b(a1.y);
            v[6] = (short)f2b(a1.z); v[7] = (short)f2b(a1.w);
            afr[ks] = v;
        }
    } else {
        const ushort* A = (const ushort*)Ap + (long)arow * HID;
#pragma unroll
        for (int ks = 0; ks < 4; ++ks) {
            afr[ks] = *(const s16x8*)(A + ks * 32 + kg * 8);
        }
    }

    float drv[4];
#pragma unroll
    for (int q = 0; q < 4; ++q) drv[q] = dinv[r0 + kg * 4 + q];

    f32x4 acc[8];
#pragma unroll
    for (int ct = 0; ct < 8; ++ct) acc[ct] = (f32x4)(0.f);

#pragma unroll
    for (int ct = 0; ct < 8; ++ct) {
        const ushort* Wrow = Wt + (ct * 16 + (l & 15)) * 136;
#pragma unroll
        for (int ks = 0; ks < 4; ++ks) {
            s16x8 bfr = *(const s16x8*)(Wrow + ks * 32 + kg * 8);
            acc[ct] = __builtin_amdgcn_mfma_f32_16x16x32_bf16(
                          afr[ks], bfr, acc[ct], 0, 0, 0);
        }
    }

#pragma unroll
    for (int ct = 0; ct < 8; ++ct) {
        int col = ct * 16 + (l & 15);
#pragma unroll
        for (int q = 0; q < 4; ++q) {
            int row = r0 + kg * 4 + q;
            H[(long)row * HID + col] = f2b(acc[ct][q] * drv[q]);
        }
    }
}

// --------------------------------------------------- column-sliced gather ---
// slice = blockIdx & 3 (XCD k -> slice k%4, 3.2 MB of hs -> L2-resident).
// 16-lane group per node; lane owns cols (sl*32+2*l16, +1) as bf16x2.
// t[d][col] = dinv[d]*(hs[d] + sum_in hs[s]) + b   (fp32, pre-LN)
__global__ __launch_bounds__(256) void agg_slice_kernel(
        const uint* __restrict__ hs2, const float* __restrict__ dinv,
        const int* __restrict__ offsEnd, const int* __restrict__ srcPerm,
        const float* __restrict__ b, float* __restrict__ t, int n) {
    const int sl    = blockIdx.x & 3;
    const int chunk = blockIdx.x >> 2;
    const int l16   = threadIdx.x & 15;
    const int grp   = threadIdx.x >> 4;          // 0..15
    const int d     = chunk * 16 + grp;
    if (d >= n) return;

    const uint* hcol = hs2 + sl * 16 + l16;      // column window of hs
    uint u = hcol[(long)d * 64];                 // self-loop (pre-scaled)
    float acc0 = b2f((ushort)u);
    float acc1 = b2f((ushort)(u >> 16));

    int beg = (d == 0) ? 0 : offsEnd[d - 1];
    int end = offsEnd[d];
    int e = beg;
    for (; e + 3 < end; e += 4) {
        int s0 = srcPerm[e],     s1 = srcPerm[e + 1];
        int s2 = srcPerm[e + 2], s3 = srcPerm[e + 3];
        uint u0 = hcol[(long)s0 * 64];
        uint u1 = hcol[(long)s1 * 64];
        uint u2 = hcol[(long)s2 * 64];
        uint u3 = hcol[(long)s3 * 64];
        acc0 += (b2f((ushort)u0) + b2f((ushort)u1))
              + (b2f((ushort)u2) + b2f((ushort)u3));
        acc1 += (b2f((ushort)(u0 >> 16)) + b2f((ushort)(u1 >> 16)))
              + (b2f((ushort)(u2 >> 16)) + b2f((ushort)(u3 >> 16)));
    }
    for (; e < end; ++e) {
        uint ue = hcol[(long)srcPerm[e] * 64];
        acc0 += b2f((ushort)ue);
        acc1 += b2f((ushort)(ue >> 16));
    }

    float dd = dinv[d];
    int col = sl * 32 + 2 * l16;
    float2 bb = *(const float2*)&b[col];
    float2 o = { acc0 * dd + bb.x, acc1 * dd + bb.y };
    *(float2*)&t[(long)d * HID + col] = o;
}

// ----------------------------------------------------- LN + GELU (pass 2) ---
// One wave per node; lane l owns cols (2l, 2l+1) of fp32 t.
template<bool OUT_F32>
__global__ __launch_bounds__(256) void ln_gelu2_kernel(
        const float* __restrict__ t, const float* __restrict__ g,
        const float* __restrict__ be,
        float* __restrict__ outf, uint* __restrict__ outb, int n) {
    int d = (int)((blockIdx.x * (long)blockDim.x + threadIdx.x) >> 6);
    int l = threadIdx.x & 63;
    if (d >= n) return;
    float2 v = *(const float2*)&t[(long)d * HID + 2 * l];
    float v0 = v.x, v1 = v.y;

    float s  = v0 + v1;
    float s2 = v0 * v0 + v1 * v1;
#pragma unroll
    for (int off = 32; off >= 1; off >>= 1) {
        s  += __shfl_xor(s,  off);
        s2 += __shfl_xor(s2, off);
    }
    float mu   = s  * (1.0f / 128.0f);
    float var  = s2 * (1.0f / 128.0f) - mu * mu;
    float rstd = rsqrtf(var + 1e-5f);
    float2 gg = *(const float2*)&g[2 * l];
    float2 ee = *(const float2*)&be[2 * l];
    float y0 = (v0 - mu) * rstd * gg.x + ee.x;
    float y1 = (v1 - mu) * rstd * gg.y + ee.y;
    float o0 = 0.5f * y0 * (1.0f + erff(y0 * 0.70710678118654752f));
    float o1 = 0.5f * y1 * (1.0f + erff(y1 * 0.70710678118654752f));

    if (OUT_F32) {
        float2 o = { o0, o1 };
        *(float2*)&outf[(long)d * HID + 2 * l] = o;
    } else {
        outb[(long)d * 64 + l] = (uint)f2b(o0) | ((uint)f2b(o1) << 16);
    }
}

// ---------------------------------------------------------------- launch ----
extern "C" void kernel_launch(void* const* d_in, const int* in_sizes, int n_in,
                              void* d_out, int out_size, void* d_ws, size_t ws_size,
                              hipStream_t stream) {
    const float* x   = (const float*)d_in[0];
    const int*   ei  = (const int*)d_in[1];   // [2, E] int32
    const float* W1  = (const float*)d_in[2];
    const float* b1  = (const float*)d_in[3];
    const float* W2  = (const float*)d_in[4];
    const float* b2  = (const float*)d_in[5];
    const float* g1  = (const float*)d_in[6];
    const float* be1 = (const float*)d_in[7];
    const float* g2  = (const float*)d_in[8];
    const float* be2 = (const float*)d_in[9];
    float* out = (float*)d_out;

    const int* src = ei;
    const int* dst = ei + N_EDGES;

    // ws: hs bf16 [N*128] | z1 bf16 [N*128] | t fp32 [N*128] | srcPerm [E]
    //     | dinv [N] | offs [N] | cnt [N] | bsum [256]   (~54 MB)
    ushort* hs      = (ushort*)d_ws;
    ushort* z1      = hs + (size_t)N_NODES * HID;
    float*  t       = (float*)(z1 + (size_t)N_NODES * HID);
    int*    srcPerm = (int*)(t + (size_t)N_NODES * HID);
    float*  dinv    = (float*)(srcPerm + N_EDGES);
    int*    offs    = (int*)(dinv + N_NODES);
    int*    cnt     = offs + N_NODES;
    int*    bsum    = cnt + N_NODES;

    const int B = 256;
    const int nodeB = (N_NODES + B - 1) / B;            // 196
    const int edgeB = (N_EDGES + B - 1) / B;
    const int gemm_blocks    = (N_NODES + 63) / 64;     // 782
    const int slice_blocks   = ((N_NODES + 15) / 16) * 4;  // 12500
    const int rowwave_blocks = (N_NODES + 3) / 4;       // 12500

    // degree -> dinv, CSR build
    zero_cnt_kernel<<<nodeB, B, 0, stream>>>(cnt, N_NODES);
    count_deg_kernel<<<edgeB, B, 0, stream>>>(dst, cnt, N_EDGES);
    reduce_dinv_kernel<<<nodeB, B, 0, stream>>>(cnt, dinv, bsum, N_NODES);
    scan_bsum_kernel<<<1, B, 0, stream>>>(bsum, nodeB);
    scan_block_kernel<<<nodeB, B, 0, stream>>>(cnt, bsum, offs, N_NODES);
    fill_csr_kernel<<<edgeB, B, 0, stream>>>(src, dst, offs, srcPerm, N_EDGES);
    // post-fill: offs[d] == end of segment d

    // ---- layer 1 ----
    gemm_mfma_kernel<true><<<gemm_blocks, B, 0, stream>>>(
        x, W1, dinv, hs, N_NODES);
    agg_slice_kernel<<<slice_blocks, B, 0, stream>>>(
        (const uint*)hs, dinv, offs, srcPerm, b1, t, N_NODES);
    ln_gelu2_kernel<false><<<rowwave_blocks, B, 0, stream>>>(
        t, g1, be1, nullptr, (uint*)z1, N_NODES);

    // ---- layer 2 ----
    gemm_mfma_kernel<false><<<gemm_blocks, B, 0, stream>>>(
        z1, W2, dinv, hs, N_NODES);
    agg_slice_kernel<<<slice_blocks, B, 0, stream>>>(
        (const uint*)hs, dinv, offs, srcPerm, b2, t, N_NODES);
    ln_gelu2_kernel<true><<<rowwave_blocks, B, 0, stream>>>(
        t, g2, be2, out, nullptr, N_NODES);
}